// Round 3
// baseline (754.177 us; speedup 1.0000x reference)
//
#include <hip/hip_runtime.h>
#include <hip/hip_bf16.h>

typedef __hip_bfloat16 bf16;

#define NB 8
#define NC 512
#define NH 64
#define NW 64
#define NHW 4096
#define NI 64

__device__ __forceinline__ float b2f(bf16 x) { return __bfloat162float(x); }
__device__ __forceinline__ bf16  f2b(float x) { return __float2bfloat16(x); }

// 64x64 tile MAC: acc[i][j] += sum_k As[k][tc+i] * Bs[k][tr+j]
// rows are the reduction dim; stride 68 floats keeps rows 16B-aligned so the
// 4 consecutive reads merge into ds_read_b128.
__device__ __forceinline__ void tile_mac(const float (*As)[68], const float (*Bs)[68],
                                         float acc[4][4], int tc, int tr) {
#pragma unroll 16
  for (int k = 0; k < 64; ++k) {
    float a0 = As[k][tc], a1 = As[k][tc + 1], a2 = As[k][tc + 2], a3 = As[k][tc + 3];
    float b0 = Bs[k][tr], b1 = Bs[k][tr + 1], b2 = Bs[k][tr + 2], b3 = Bs[k][tr + 3];
    acc[0][0] += a0 * b0; acc[0][1] += a0 * b1; acc[0][2] += a0 * b2; acc[0][3] += a0 * b3;
    acc[1][0] += a1 * b0; acc[1][1] += a1 * b1; acc[1][2] += a1 * b2; acc[1][3] += a1 * b3;
    acc[2][0] += a2 * b0; acc[2][1] += a2 * b1; acc[2][2] += a2 * b2; acc[2][3] += a2 * b3;
    acc[3][0] += a3 * b0; acc[3][1] += a3 * b1; acc[3][2] += a3 * b2; acc[3][3] += a3 * b3;
  }
}

// out[b, o0+o, px] = bias[o0+o] + sum_c W[o0+o, c] * X[b, c, px]  (f32 in, bf16 out)
__global__ __launch_bounds__(256) void proj_kernel(const float* __restrict__ X,
                                                   const float* __restrict__ Wm,
                                                   const float* __restrict__ bias,
                                                   bf16* __restrict__ out, int M) {
  __shared__ float As[64][68];  // As[c][o]
  __shared__ float Bs[64][68];  // Bs[c][px]
  int t = threadIdx.x, lane = t & 63, row4 = t >> 6;
  int b = blockIdx.x >> 6, pt = blockIdx.x & 63;
  int px0 = pt * 64;
  int o0 = blockIdx.y * 64;
  float acc[4][4] = {};
  const float* Xb = X + (size_t)b * NC * NHW + px0;
  for (int c0 = 0; c0 < NC; c0 += 64) {
    for (int c = row4; c < 64; c += 4) {
      As[c][lane] = Wm[(size_t)(o0 + lane) * NC + c0 + c];   // W small, L2-hot
      Bs[c][lane] = Xb[(size_t)(c0 + c) * NHW + lane];       // coalesced
    }
    __syncthreads();
    tile_mac(As, Bs, acc, (t & 15) * 4, (t >> 4) * 4);
    __syncthreads();
  }
  int tc = (t & 15) * 4, tr = (t >> 4) * 4;
  bf16* ob = out + (size_t)(b * M + o0) * NHW + px0;
#pragma unroll
  for (int i = 0; i < 4; ++i) {
    float bi = bias[o0 + tc + i];
#pragma unroll
    for (int j = 0; j < 4; ++j)
      ob[(size_t)(tc + i) * NHW + tr + j] = f2b(acc[i][j] + bi);
  }
}

// y==0: eH[b,h,w,g] = sum_o pq[b,o,h,w]*pk[b,o,g,w], diag h==g masked, fixed w=q
// y==1: eW[b,h,w,f] = sum_o pq[b,o,h,w]*pk[b,o,h,f],               fixed h=q
// att layout: att[((b*64+h)*64+w)*128 + (g | 64+f)]
__global__ __launch_bounds__(256) void score_kernel(const bf16* __restrict__ pq,
                                                    const bf16* __restrict__ pk,
                                                    float* __restrict__ att) {
  __shared__ float As[64][68];
  __shared__ float Bs[64][68];
  int t = threadIdx.x, lane = t & 63, row4 = t >> 6;
  int b = blockIdx.x >> 6, q = blockIdx.x & 63;
  bool isH = (blockIdx.y == 0);
  const bf16* pqb = pq + (size_t)b * NI * NHW;
  const bf16* pkb = pk + (size_t)b * NI * NHW;
  for (int o = row4; o < 64; o += 4) {
    size_t base = (size_t)o * NHW;
    if (isH) {
      As[o][lane] = b2f(pqb[base + (size_t)lane * NW + q]);
      Bs[o][lane] = b2f(pkb[base + (size_t)lane * NW + q]);
    } else {
      As[o][lane] = b2f(pqb[base + (size_t)q * NW + lane]);
      Bs[o][lane] = b2f(pkb[base + (size_t)q * NW + lane]);
    }
  }
  __syncthreads();
  int tc = (t & 15) * 4, tr = (t >> 4) * 4;
  float acc[4][4] = {};
  tile_mac(As, Bs, acc, tc, tr);
#pragma unroll
  for (int i = 0; i < 4; ++i)
#pragma unroll
    for (int j = 0; j < 4; ++j) {
      if (isH) {
        int h = tc + i, g = tr + j;
        float v = (h == g) ? -1e30f : acc[i][j];
        att[((size_t)(b * 64 + h) * 64 + q) * 128 + g] = v;
      } else {
        int w = tc + i, f = tr + j;
        att[((size_t)(b * 64 + q) * 64 + w) * 128 + 64 + f] = acc[i][j];
      }
    }
}

__global__ __launch_bounds__(256) void softmax_kernel(float* __restrict__ att) {
  int wave = threadIdx.x >> 6, lane = threadIdx.x & 63;
  int p = blockIdx.x * 4 + wave;
  float* row = att + (size_t)p * 128;
  float v0 = row[lane], v1 = row[lane + 64];
  float m = fmaxf(v0, v1);
#pragma unroll
  for (int off = 32; off; off >>= 1) m = fmaxf(m, __shfl_xor(m, off));
  float e0 = __expf(v0 - m), e1 = __expf(v1 - m);
  float s = e0 + e1;
#pragma unroll
  for (int off = 32; off; off >>= 1) s += __shfl_xor(s, off);
  float inv = 1.0f / s;
  row[lane] = e0 * inv;
  row[lane + 64] = e1 * inv;
}

// transpose last two 64x64 dims (bf16 planes)
__global__ __launch_bounds__(256) void transpose_kernel(const bf16* __restrict__ in,
                                                        bf16* __restrict__ out) {
  __shared__ float s[64][65];
  int lane = threadIdx.x & 63, row4 = threadIdx.x >> 6;
  const bf16* ip = in + (size_t)blockIdx.x * 4096;
  bf16* op = out + (size_t)blockIdx.x * 4096;
  for (int r = row4; r < 64; r += 4) s[r][lane] = b2f(ip[r * 64 + lane]);
  __syncthreads();
  for (int r = row4; r < 64; r += 4) op[r * 64 + lane] = f2b(s[lane][r]);
}

// mode 0: block (b*64+w, ct): t1T[b,c,w,h] = sum_g pv[b,c,g,w]*attH[b,h,w,g] -> bf16 ws
// mode 1: block (b*64+h, ct): t2 [b,c,h,w] = sum_f pv[b,c,h,f]*attW[b,h,w,f] -> f32 d_out
__global__ __launch_bounds__(256) void apply_kernel(const bf16* __restrict__ pvx,
                                                    const float* __restrict__ att,
                                                    void* outp,
                                                    int mode, int strided, int write_f32) {
  __shared__ float As[64][68];  // As[k][c], k = g or f
  __shared__ float Bs[64][68];  // Bs[k][h or w]
  int t = threadIdx.x, lane = t & 63, row4 = t >> 6;
  int b = blockIdx.x >> 6, q = blockIdx.x & 63;  // q = w (mode0) or h (mode1)
  int c0 = blockIdx.y * 64;
  for (int r = row4; r < 64; r += 4) {
    if (mode == 0 && strided)
      As[lane][r] = b2f(pvx[(size_t)(b * NC + c0 + r) * 4096 + (size_t)lane * 64 + q]);
    else
      As[lane][r] = b2f(pvx[((size_t)(b * NC + c0 + r) * 64 + q) * 64 + lane]);
    if (mode == 0)
      Bs[lane][r] = att[((size_t)(b * 64 + r) * 64 + q) * 128 + lane];        // attH, r=h
    else
      Bs[lane][r] = att[((size_t)(b * 64 + q) * 64 + r) * 128 + 64 + lane];   // attW, r=w
  }
  __syncthreads();
  int tc = (t & 15) * 4, tr = (t >> 4) * 4;
  float acc[4][4] = {};
  tile_mac(As, Bs, acc, tc, tr);
#pragma unroll
  for (int i = 0; i < 4; ++i)
#pragma unroll
    for (int j = 0; j < 4; ++j) {
      size_t idx = ((size_t)(b * NC + c0 + tc + i) * 64 + q) * 64 + tr + j;
      if (write_f32) ((float*)outp)[idx] = acc[i][j];
      else           ((bf16*)outp)[idx]  = f2b(acc[i][j]);
    }
}

// out[b,c,h,w] = gamma*(t1T[b,c,w,h] + t2[b,c,h,w]) + value[b,c,h,w]   (f32 out)
// t2 aliases out (f32, same addresses, same thread) — no __restrict__ on these.
__global__ __launch_bounds__(256) void combine_kernel(const bf16* __restrict__ t1T,
                                                      const float* t2,
                                                      const float* __restrict__ value,
                                                      const float* __restrict__ gamma,
                                                      float* out) {
  __shared__ float s[64][65];
  int lane = threadIdx.x & 63, row4 = threadIdx.x >> 6;
  size_t p = blockIdx.x;  // b*512 + c
  float g = gamma[0];
  const bf16* ip = t1T + p * 4096;
  for (int r = row4; r < 64; r += 4) s[r][lane] = b2f(ip[r * 64 + lane]);  // s[w][h]
  __syncthreads();
  const float* t2p = t2 + p * 4096;
  const float* vp = value + p * 4096;
  float* op = out + p * 4096;
  for (int h = row4; h < 64; h += 4) {
    float t2v = t2p[h * 64 + lane];
    float o = g * (s[lane][h] + t2v) + vp[h * 64 + lane];
    op[h * 64 + lane] = o;
  }
}

extern "C" void kernel_launch(void* const* d_in, const int* in_sizes, int n_in,
                              void* d_out, int out_size, void* d_ws, size_t ws_size,
                              hipStream_t stream) {
  const float* query = (const float*)d_in[0];
  const float* key_t = (const float*)d_in[1];
  const float* value = (const float*)d_in[2];
  const float* Wq    = (const float*)d_in[3];
  const float* bq    = (const float*)d_in[4];
  const float* Wk    = (const float*)d_in[5];
  const float* bk    = (const float*)d_in[6];
  const float* Wv    = (const float*)d_in[7];
  const float* bv    = (const float*)d_in[8];
  const float* gamma = (const float*)d_in[9];
  float* out = (float*)d_out;

  // ws layout: pq@0(4) pk@4(4) att@8(16,f32) pv@24(32) t1T@56(32) [pvT@88(32)]
  // t2 is f32 and lives directly in d_out (written by apply mode 1 at final
  // positions, read+overwritten by the same thread in combine).
  // COMPACT needs 88 MB; FULL (with pvT) needs 120 MB.
  char* ws = (char*)d_ws;
  bool full = ws_size >= (120ull << 20);
  bf16*  pq  = (bf16*)(ws);
  bf16*  pk  = (bf16*)(ws + (4ull << 20));
  float* att = (float*)(ws + (8ull << 20));
  bf16*  pv  = (bf16*)(ws + (24ull << 20));
  bf16*  t1T = (bf16*)(ws + (56ull << 20));
  bf16*  pvT = (bf16*)(ws + (88ull << 20));

  dim3 blk(256);
  proj_kernel<<<dim3(NB * 64, 1), blk, 0, stream>>>(query, Wq, bq, pq, NI);
  proj_kernel<<<dim3(NB * 64, 1), blk, 0, stream>>>(key_t, Wk, bk, pk, NI);
  proj_kernel<<<dim3(NB * 64, 8), blk, 0, stream>>>(value, Wv, bv, pv, NC);
  if (full) transpose_kernel<<<NB * NC, blk, 0, stream>>>(pv, pvT);
  score_kernel<<<dim3(NB * 64, 2), blk, 0, stream>>>(pq, pk, att);
  softmax_kernel<<<NB * NHW / 4, blk, 0, stream>>>(att);
  apply_kernel<<<dim3(NB * 64, 8), blk, 0, stream>>>(full ? pvT : pv, att, t1T, 0, full ? 0 : 1, 0);
  apply_kernel<<<dim3(NB * 64, 8), blk, 0, stream>>>(pv, att, out, 1, 0, 1);
  combine_kernel<<<NB * NC, blk, 0, stream>>>(t1T, out, value, gamma, out);
}

// Round 4
// 503.026 us; speedup vs baseline: 1.4993x; 1.4993x over previous
//
#include <hip/hip_runtime.h>
#include <hip/hip_bf16.h>

typedef __hip_bfloat16 bf16;
typedef __bf16 v8bf __attribute__((ext_vector_type(8)));
typedef float v4f __attribute__((ext_vector_type(4)));

#define NB 8
#define NC 512
#define NH 64
#define NW 64
#define NHW 4096
#define NI 64

__device__ __forceinline__ float b2f(bf16 x) { return __bfloat162float(x); }
__device__ __forceinline__ bf16  f2b(float x) { return __float2bfloat16(x); }

// ---------------- MFMA projection: out[b,o,px] = bias[o] + sum_c W[o,c] X[b,c,px]
// TM x TN block tile, BK=64, 4 waves each computing 64x64 via 4x4 mfma_16x16x32.
// LDS pitch 72 bf16 (144 B): 16B-aligned frags, 2-way-max bank aliasing (free).
// A (W) is [m][k] naturally; B (X) is [k][n] -> transposed during staging via
// per-c coalesced dword loads (lane = px) + packed 16B LDS writes.
template <int TM, int TN>
__global__ __launch_bounds__(256) void proj_mfma(const float* __restrict__ X0,
                                                 const float* __restrict__ W0,
                                                 const float* __restrict__ b0,
                                                 bf16* __restrict__ o0p,
                                                 const float* __restrict__ X1,
                                                 const float* __restrict__ W1,
                                                 const float* __restrict__ b1,
                                                 bf16* __restrict__ o1p,
                                                 int M) {
  __shared__ __align__(16) __bf16 As[TM * 72];
  __shared__ __align__(16) __bf16 Bs[TN * 72];
  const float* X = (blockIdx.z == 0) ? X0 : X1;
  const float* Wm = (blockIdx.z == 0) ? W0 : W1;
  const float* bias = (blockIdx.z == 0) ? b0 : b1;
  bf16* out = (blockIdx.z == 0) ? o0p : o1p;

  const int NT = 4096 / TN;
  int t = threadIdx.x;
  int b = blockIdx.x / NT, nt = blockIdx.x % NT;
  int px0 = nt * TN, o0 = blockIdx.y * TM;
  int wave = t >> 6, lane = t & 63;
  int wm = (TM == 128) ? (wave >> 1) * 64 : 0;
  int wn = (TM == 128) ? (wave & 1) * 64 : wave * 64;
  int row16 = lane & 15, quad = lane >> 4;

  v4f acc[4][4] = {};
  const float* Xb = X + (size_t)b * NC * NHW + px0;

  const int CL = TN / 4;            // c's per thread in B staging
  int bp = t & (TN - 1);            // px owned in B staging
  int bch = (t / TN) * CL;          // c-chunk start

  for (int k0 = 0; k0 < NC; k0 += 64) {
    // ---- stage A: TM x 64 of W, convert f32->bf16
    for (int f = t; f < TM * 16; f += 256) {
      int m = f >> 4, c4 = (f & 15) * 4;
      float4 w = *(const float4*)&Wm[(size_t)(o0 + m) * NC + k0 + c4];
      union { __bf16 h[4]; uint2 u; } pk;
      pk.h[0] = (__bf16)w.x; pk.h[1] = (__bf16)w.y;
      pk.h[2] = (__bf16)w.z; pk.h[3] = (__bf16)w.w;
      *(uint2*)&As[m * 72 + c4] = pk.u;
    }
    // ---- stage B: transpose [c][px] -> Bs[px][c]
    for (int cc = 0; cc < CL; cc += 8) {
      float r[8];
#pragma unroll
      for (int j = 0; j < 8; ++j)
        r[j] = Xb[(size_t)(k0 + bch + cc + j) * NHW + bp];
      union { __bf16 h[8]; uint4 u; } pk;
#pragma unroll
      for (int j = 0; j < 8; ++j) pk.h[j] = (__bf16)r[j];
      *(uint4*)&Bs[bp * 72 + bch + cc] = pk.u;
    }
    __syncthreads();
#pragma unroll
    for (int ks = 0; ks < 2; ++ks) {
      v8bf af[4], bf[4];
#pragma unroll
      for (int i = 0; i < 4; ++i) {
        af[i] = *(const v8bf*)&As[(wm + i * 16 + row16) * 72 + ks * 32 + quad * 8];
        bf[i] = *(const v8bf*)&Bs[(wn + i * 16 + row16) * 72 + ks * 32 + quad * 8];
      }
#pragma unroll
      for (int mi = 0; mi < 4; ++mi)
#pragma unroll
        for (int ni = 0; ni < 4; ++ni)
          acc[mi][ni] = __builtin_amdgcn_mfma_f32_16x16x32_bf16(af[mi], bf[ni],
                                                                acc[mi][ni], 0, 0, 0);
    }
    __syncthreads();
  }
  // ---- epilogue: C/D layout col=lane&15, row=quad*4+r
#pragma unroll
  for (int mi = 0; mi < 4; ++mi)
#pragma unroll
    for (int r = 0; r < 4; ++r) {
      int m = wm + mi * 16 + quad * 4 + r;
      float bi = bias[o0 + m];
      bf16* orow = out + (size_t)(b * M + o0 + m) * NHW + px0 + wn + row16;
#pragma unroll
      for (int ni = 0; ni < 4; ++ni)
        orow[ni * 16] = f2b(acc[mi][ni][r] + bi);
    }
}

// ---------------- VALU 64x64 tile MAC (score / apply), unchanged from R3
__device__ __forceinline__ void tile_mac(const float (*As)[68], const float (*Bs)[68],
                                         float acc[4][4], int tc, int tr) {
#pragma unroll 16
  for (int k = 0; k < 64; ++k) {
    float a0 = As[k][tc], a1 = As[k][tc + 1], a2 = As[k][tc + 2], a3 = As[k][tc + 3];
    float b0 = Bs[k][tr], b1 = Bs[k][tr + 1], b2 = Bs[k][tr + 2], b3 = Bs[k][tr + 3];
    acc[0][0] += a0 * b0; acc[0][1] += a0 * b1; acc[0][2] += a0 * b2; acc[0][3] += a0 * b3;
    acc[1][0] += a1 * b0; acc[1][1] += a1 * b1; acc[1][2] += a1 * b2; acc[1][3] += a1 * b3;
    acc[2][0] += a2 * b0; acc[2][1] += a2 * b1; acc[2][2] += a2 * b2; acc[2][3] += a2 * b3;
    acc[3][0] += a3 * b0; acc[3][1] += a3 * b1; acc[3][2] += a3 * b2; acc[3][3] += a3 * b3;
  }
}

// y==0: eH[b,h,w,g] = sum_o pq[b,o,h,w]*pk[b,o,g,w], diag masked, fixed w=q
// y==1: eW[b,h,w,f] = sum_o pq[b,o,h,w]*pk[b,o,h,f],              fixed h=q
__global__ __launch_bounds__(256) void score_kernel(const bf16* __restrict__ pq,
                                                    const bf16* __restrict__ pk,
                                                    float* __restrict__ att) {
  __shared__ float As[64][68];
  __shared__ float Bs[64][68];
  int t = threadIdx.x, lane = t & 63, row4 = t >> 6;
  int b = blockIdx.x >> 6, q = blockIdx.x & 63;
  bool isH = (blockIdx.y == 0);
  const bf16* pqb = pq + (size_t)b * NI * NHW;
  const bf16* pkb = pk + (size_t)b * NI * NHW;
  for (int o = row4; o < 64; o += 4) {
    size_t base = (size_t)o * NHW;
    if (isH) {
      As[o][lane] = b2f(pqb[base + (size_t)lane * NW + q]);
      Bs[o][lane] = b2f(pkb[base + (size_t)lane * NW + q]);
    } else {
      As[o][lane] = b2f(pqb[base + (size_t)q * NW + lane]);
      Bs[o][lane] = b2f(pkb[base + (size_t)q * NW + lane]);
    }
  }
  __syncthreads();
  int tc = (t & 15) * 4, tr = (t >> 4) * 4;
  float acc[4][4] = {};
  tile_mac(As, Bs, acc, tc, tr);
#pragma unroll
  for (int i = 0; i < 4; ++i)
#pragma unroll
    for (int j = 0; j < 4; ++j) {
      if (isH) {
        int h = tc + i, g = tr + j;
        float v = (h == g) ? -1e30f : acc[i][j];
        att[((size_t)(b * 64 + h) * 64 + q) * 128 + g] = v;
      } else {
        int w = tc + i, f = tr + j;
        att[((size_t)(b * 64 + q) * 64 + w) * 128 + 64 + f] = acc[i][j];
      }
    }
}

__global__ __launch_bounds__(256) void softmax_kernel(float* __restrict__ att) {
  int wave = threadIdx.x >> 6, lane = threadIdx.x & 63;
  int p = blockIdx.x * 4 + wave;
  float* row = att + (size_t)p * 128;
  float v0 = row[lane], v1 = row[lane + 64];
  float m = fmaxf(v0, v1);
#pragma unroll
  for (int off = 32; off; off >>= 1) m = fmaxf(m, __shfl_xor(m, off));
  float e0 = __expf(v0 - m), e1 = __expf(v1 - m);
  float s = e0 + e1;
#pragma unroll
  for (int off = 32; off; off >>= 1) s += __shfl_xor(s, off);
  float inv = 1.0f / s;
  row[lane] = e0 * inv;
  row[lane + 64] = e1 * inv;
}

__global__ __launch_bounds__(256) void transpose_kernel(const bf16* __restrict__ in,
                                                        bf16* __restrict__ out) {
  __shared__ float s[64][65];
  int lane = threadIdx.x & 63, row4 = threadIdx.x >> 6;
  const bf16* ip = in + (size_t)blockIdx.x * 4096;
  bf16* op = out + (size_t)blockIdx.x * 4096;
  for (int r = row4; r < 64; r += 4) s[r][lane] = b2f(ip[r * 64 + lane]);
  __syncthreads();
  for (int r = row4; r < 64; r += 4) op[r * 64 + lane] = f2b(s[lane][r]);
}

// mode 0: t1T[b,c,w,h] = sum_g pv[b,c,g,w]*attH[b,h,w,g] -> bf16 ws
// mode 1: t2 [b,c,h,w] = sum_f pv[b,c,h,f]*attW[b,h,w,f] -> f32 d_out
__global__ __launch_bounds__(256) void apply_kernel(const bf16* __restrict__ pvx,
                                                    const float* __restrict__ att,
                                                    void* outp,
                                                    int mode, int strided, int write_f32) {
  __shared__ float As[64][68];
  __shared__ float Bs[64][68];
  int t = threadIdx.x, lane = t & 63, row4 = t >> 6;
  int b = blockIdx.x >> 6, q = blockIdx.x & 63;
  int c0 = blockIdx.y * 64;
  for (int r = row4; r < 64; r += 4) {
    if (mode == 0 && strided)
      As[lane][r] = b2f(pvx[(size_t)(b * NC + c0 + r) * 4096 + (size_t)lane * 64 + q]);
    else
      As[lane][r] = b2f(pvx[((size_t)(b * NC + c0 + r) * 64 + q) * 64 + lane]);
    if (mode == 0)
      Bs[lane][r] = att[((size_t)(b * 64 + r) * 64 + q) * 128 + lane];
    else
      Bs[lane][r] = att[((size_t)(b * 64 + q) * 64 + r) * 128 + 64 + lane];
  }
  __syncthreads();
  int tc = (t & 15) * 4, tr = (t >> 4) * 4;
  float acc[4][4] = {};
  tile_mac(As, Bs, acc, tc, tr);
#pragma unroll
  for (int i = 0; i < 4; ++i)
#pragma unroll
    for (int j = 0; j < 4; ++j) {
      size_t idx = ((size_t)(b * NC + c0 + tc + i) * 64 + q) * 64 + tr + j;
      if (write_f32) ((float*)outp)[idx] = acc[i][j];
      else           ((bf16*)outp)[idx]  = f2b(acc[i][j]);
    }
}

// out = gamma*(t1T^T + t2) + value ; t2 aliases out (same addr, same thread)
__global__ __launch_bounds__(256) void combine_kernel(const bf16* __restrict__ t1T,
                                                      const float* t2,
                                                      const float* __restrict__ value,
                                                      const float* __restrict__ gamma,
                                                      float* out) {
  __shared__ float s[64][65];
  int lane = threadIdx.x & 63, row4 = threadIdx.x >> 6;
  size_t p = blockIdx.x;
  float g = gamma[0];
  const bf16* ip = t1T + p * 4096;
  for (int r = row4; r < 64; r += 4) s[r][lane] = b2f(ip[r * 64 + lane]);
  __syncthreads();
  const float* t2p = t2 + p * 4096;
  const float* vp = value + p * 4096;
  float* op = out + p * 4096;
  for (int h = row4; h < 64; h += 4) {
    float t2v = t2p[h * 64 + lane];
    op[h * 64 + lane] = g * (s[lane][h] + t2v) + vp[h * 64 + lane];
  }
}

extern "C" void kernel_launch(void* const* d_in, const int* in_sizes, int n_in,
                              void* d_out, int out_size, void* d_ws, size_t ws_size,
                              hipStream_t stream) {
  const float* query = (const float*)d_in[0];
  const float* key_t = (const float*)d_in[1];
  const float* value = (const float*)d_in[2];
  const float* Wq    = (const float*)d_in[3];
  const float* bq    = (const float*)d_in[4];
  const float* Wk    = (const float*)d_in[5];
  const float* bk    = (const float*)d_in[6];
  const float* Wv    = (const float*)d_in[7];
  const float* bv    = (const float*)d_in[8];
  const float* gamma = (const float*)d_in[9];
  float* out = (float*)d_out;

  // ws: pq@0(4) pk@4(4) att@8(16,f32) pv@24(32) t1T@56(32) [pvT@88(32)]
  char* ws = (char*)d_ws;
  bool full = ws_size >= (120ull << 20);
  bf16*  pq  = (bf16*)(ws);
  bf16*  pk  = (bf16*)(ws + (4ull << 20));
  float* att = (float*)(ws + (8ull << 20));
  bf16*  pv  = (bf16*)(ws + (24ull << 20));
  bf16*  t1T = (bf16*)(ws + (56ull << 20));
  bf16*  pvT = (bf16*)(ws + (88ull << 20));

  dim3 blk(256);
  // pq + pk fused in one launch (z selects tensor set); 256 blocks = full chip
  proj_mfma<64, 256><<<dim3(NB * 16, 1, 2), blk, 0, stream>>>(
      query, Wq, bq, pq, key_t, Wk, bk, pk, NI);
  // pv: 128x128 tiles, 1024 blocks
  proj_mfma<128, 128><<<dim3(NB * 32, 4, 1), blk, 0, stream>>>(
      value, Wv, bv, pv, value, Wv, bv, pv, NC);
  if (full) transpose_kernel<<<NB * NC, blk, 0, stream>>>(pv, pvT);
  score_kernel<<<dim3(NB * 64, 2), blk, 0, stream>>>(pq, pk, att);
  softmax_kernel<<<NB * NHW / 4, blk, 0, stream>>>(att);
  apply_kernel<<<dim3(NB * 64, 8), blk, 0, stream>>>(full ? pvT : pv, att, t1T, 0, full ? 0 : 1, 0);
  apply_kernel<<<dim3(NB * 64, 8), blk, 0, stream>>>(pv, att, out, 1, 0, 1);
  combine_kernel<<<NB * NC, blk, 0, stream>>>(t1T, out, value, gamma, out);
}

// Round 5
// 447.489 us; speedup vs baseline: 1.6854x; 1.1241x over previous
//
#include <hip/hip_runtime.h>
#include <hip/hip_bf16.h>

typedef __hip_bfloat16 bf16;
typedef __bf16 v8bf __attribute__((ext_vector_type(8)));
typedef float v4f __attribute__((ext_vector_type(4)));

#define NB 8
#define NC 512
#define NH 64
#define NW 64
#define NHW 4096
#define NI 64

__device__ __forceinline__ float b2f(bf16 x) { return __bfloat162float(x); }
__device__ __forceinline__ bf16  f2b(float x) { return __float2bfloat16(x); }

// ---- prep: vT[b,px,c] = bf16(value[b,c,px])  +  Wb = bf16(Wv)
__global__ __launch_bounds__(256) void prep_kernel(const float* __restrict__ value,
                                                   const float* __restrict__ Wv,
                                                   bf16* __restrict__ vT,
                                                   bf16* __restrict__ Wb) {
  int t = threadIdx.x;
  if (blockIdx.x < 4096) {
    __shared__ float s[64][65];
    int i = blockIdx.x;
    int b = i >> 9, rem = i & 511;
    int c0 = (rem >> 6) * 64, px0 = (rem & 63) * 64;
    int lane = t & 63, row4 = t >> 6;
    const float* vp = value + (size_t)b * NC * NHW;
    for (int r = row4; r < 64; r += 4)
      s[r][lane] = vp[(size_t)(c0 + r) * NHW + px0 + lane];
    __syncthreads();
    bf16* op = vT + (size_t)b * NHW * NC;
    for (int r = row4; r < 64; r += 4)
      op[(size_t)(px0 + r) * NC + c0 + lane] = f2b(s[lane][r]);
  } else {
    size_t idx = (size_t)(blockIdx.x - 4096) * 1024 + t * 4;
    float4 w = *(const float4*)&Wv[idx];
    union { __bf16 h[4]; uint2 u; } pk;
    pk.h[0] = (__bf16)w.x; pk.h[1] = (__bf16)w.y;
    pk.h[2] = (__bf16)w.z; pk.h[3] = (__bf16)w.w;
    *(uint2*)&Wb[idx] = pk.u;
  }
}

// ---- pv GEMM: pv[b,o,px] = bias[o] + sum_c Wb[o,c] * vT[b,px,c]
// 128x128 tile, BK=64, both operands K-contiguous bf16, LDS pitch 72.
__global__ __launch_bounds__(256) void gemm_nt(const bf16* __restrict__ Wb,
                                               const bf16* __restrict__ vT,
                                               const float* __restrict__ bias,
                                               bf16* __restrict__ out) {
  __shared__ __align__(16) __bf16 As[128 * 72];
  __shared__ __align__(16) __bf16 Bs[128 * 72];
  int t = threadIdx.x;
  int b = blockIdx.x >> 5, pxt = blockIdx.x & 31;
  int px0 = pxt * 128, o0 = blockIdx.y * 128;
  int wave = t >> 6, lane = t & 63;
  int wm = (wave >> 1) * 64, wn = (wave & 1) * 64;
  int row16 = lane & 15, quad = lane >> 4;
  v4f acc[4][4] = {};
  const bf16* Bp = vT + ((size_t)b * NHW + px0) * NC;
  for (int k0 = 0; k0 < NC; k0 += 64) {
#pragma unroll
    for (int ii = 0; ii < 4; ++ii) {
      int i = t + ii * 256;
      int m = i >> 3, ch = i & 7;
      *(uint4*)&As[m * 72 + ch * 8] = *(const uint4*)&Wb[(size_t)(o0 + m) * NC + k0 + ch * 8];
      *(uint4*)&Bs[m * 72 + ch * 8] = *(const uint4*)&Bp[(size_t)m * NC + k0 + ch * 8];
    }
    __syncthreads();
#pragma unroll
    for (int ks = 0; ks < 2; ++ks) {
      v8bf af[4], bf[4];
#pragma unroll
      for (int i = 0; i < 4; ++i) {
        af[i] = *(const v8bf*)&As[(wm + i * 16 + row16) * 72 + ks * 32 + quad * 8];
        bf[i] = *(const v8bf*)&Bs[(wn + i * 16 + row16) * 72 + ks * 32 + quad * 8];
      }
#pragma unroll
      for (int mi = 0; mi < 4; ++mi)
#pragma unroll
        for (int ni = 0; ni < 4; ++ni)
          acc[mi][ni] = __builtin_amdgcn_mfma_f32_16x16x32_bf16(af[mi], bf[ni],
                                                                acc[mi][ni], 0, 0, 0);
    }
    __syncthreads();
  }
#pragma unroll
  for (int mi = 0; mi < 4; ++mi)
#pragma unroll
    for (int r = 0; r < 4; ++r) {
      int m = wm + mi * 16 + quad * 4 + r;
      float bi = bias[o0 + m];
      bf16* orow = out + (size_t)(b * NC + o0 + m) * NHW + px0 + wn + row16;
#pragma unroll
      for (int ni = 0; ni < 4; ++ni)
        orow[ni * 16] = f2b(acc[mi][ni][r] + bi);
    }
}

// ---- pq/pk projection (unchanged from R4): out[b,o,px] = bias + W X, f32 in
template <int TM, int TN>
__global__ __launch_bounds__(256) void proj_mfma(const float* __restrict__ X0,
                                                 const float* __restrict__ W0,
                                                 const float* __restrict__ b0,
                                                 bf16* __restrict__ o0p,
                                                 const float* __restrict__ X1,
                                                 const float* __restrict__ W1,
                                                 const float* __restrict__ b1,
                                                 bf16* __restrict__ o1p,
                                                 int M) {
  __shared__ __align__(16) __bf16 As[TM * 72];
  __shared__ __align__(16) __bf16 Bs[TN * 72];
  const float* X = (blockIdx.z == 0) ? X0 : X1;
  const float* Wm = (blockIdx.z == 0) ? W0 : W1;
  const float* bias = (blockIdx.z == 0) ? b0 : b1;
  bf16* out = (blockIdx.z == 0) ? o0p : o1p;
  const int NT = 4096 / TN;
  int t = threadIdx.x;
  int b = blockIdx.x / NT, nt = blockIdx.x % NT;
  int px0 = nt * TN, o0 = blockIdx.y * TM;
  int wave = t >> 6, lane = t & 63;
  int wm = (TM == 128) ? (wave >> 1) * 64 : 0;
  int wn = (TM == 128) ? (wave & 1) * 64 : wave * 64;
  int row16 = lane & 15, quad = lane >> 4;
  v4f acc[4][4] = {};
  const float* Xb = X + (size_t)b * NC * NHW + px0;
  const int CL = TN / 4;
  int bp = t & (TN - 1);
  int bch = (t / TN) * CL;
  for (int k0 = 0; k0 < NC; k0 += 64) {
    for (int f = t; f < TM * 16; f += 256) {
      int m = f >> 4, c4 = (f & 15) * 4;
      float4 w = *(const float4*)&Wm[(size_t)(o0 + m) * NC + k0 + c4];
      union { __bf16 h[4]; uint2 u; } pk;
      pk.h[0] = (__bf16)w.x; pk.h[1] = (__bf16)w.y;
      pk.h[2] = (__bf16)w.z; pk.h[3] = (__bf16)w.w;
      *(uint2*)&As[m * 72 + c4] = pk.u;
    }
    for (int cc = 0; cc < CL; cc += 8) {
      float r[8];
#pragma unroll
      for (int j = 0; j < 8; ++j)
        r[j] = Xb[(size_t)(k0 + bch + cc + j) * NHW + bp];
      union { __bf16 h[8]; uint4 u; } pk;
#pragma unroll
      for (int j = 0; j < 8; ++j) pk.h[j] = (__bf16)r[j];
      *(uint4*)&Bs[bp * 72 + bch + cc] = pk.u;
    }
    __syncthreads();
#pragma unroll
    for (int ks = 0; ks < 2; ++ks) {
      v8bf af[4], bf[4];
#pragma unroll
      for (int i = 0; i < 4; ++i) {
        af[i] = *(const v8bf*)&As[(wm + i * 16 + row16) * 72 + ks * 32 + quad * 8];
        bf[i] = *(const v8bf*)&Bs[(wn + i * 16 + row16) * 72 + ks * 32 + quad * 8];
      }
#pragma unroll
      for (int mi = 0; mi < 4; ++mi)
#pragma unroll
        for (int ni = 0; ni < 4; ++ni)
          acc[mi][ni] = __builtin_amdgcn_mfma_f32_16x16x32_bf16(af[mi], bf[ni],
                                                                acc[mi][ni], 0, 0, 0);
    }
    __syncthreads();
  }
#pragma unroll
  for (int mi = 0; mi < 4; ++mi)
#pragma unroll
    for (int r = 0; r < 4; ++r) {
      int m = wm + mi * 16 + quad * 4 + r;
      float bi = bias[o0 + m];
      bf16* orow = out + (size_t)(b * M + o0 + m) * NHW + px0 + wn + row16;
#pragma unroll
      for (int ni = 0; ni < 4; ++ni)
        orow[ni * 16] = f2b(acc[mi][ni][r] + bi);
    }
}

// ---- score (VALU, unchanged): writes att[((b*64+h)*64+w)*128 + (g | 64+f)]
__device__ __forceinline__ void tile_mac(const float (*As)[68], const float (*Bs)[68],
                                         float acc[4][4], int tc, int tr) {
#pragma unroll 16
  for (int k = 0; k < 64; ++k) {
    float a0 = As[k][tc], a1 = As[k][tc + 1], a2 = As[k][tc + 2], a3 = As[k][tc + 3];
    float b0 = Bs[k][tr], b1 = Bs[k][tr + 1], b2 = Bs[k][tr + 2], b3 = Bs[k][tr + 3];
    acc[0][0] += a0 * b0; acc[0][1] += a0 * b1; acc[0][2] += a0 * b2; acc[0][3] += a0 * b3;
    acc[1][0] += a1 * b0; acc[1][1] += a1 * b1; acc[1][2] += a1 * b2; acc[1][3] += a1 * b3;
    acc[2][0] += a2 * b0; acc[2][1] += a2 * b1; acc[2][2] += a2 * b2; acc[2][3] += a2 * b3;
    acc[3][0] += a3 * b0; acc[3][1] += a3 * b1; acc[3][2] += a3 * b2; acc[3][3] += a3 * b3;
  }
}

__global__ __launch_bounds__(256) void score_kernel(const bf16* __restrict__ pq,
                                                    const bf16* __restrict__ pk,
                                                    float* __restrict__ att) {
  __shared__ float As[64][68];
  __shared__ float Bs[64][68];
  int t = threadIdx.x, lane = t & 63, row4 = t >> 6;
  int b = blockIdx.x >> 6, q = blockIdx.x & 63;
  bool isH = (blockIdx.y == 0);
  const bf16* pqb = pq + (size_t)b * NI * NHW;
  const bf16* pkb = pk + (size_t)b * NI * NHW;
  for (int o = row4; o < 64; o += 4) {
    size_t base = (size_t)o * NHW;
    if (isH) {
      As[o][lane] = b2f(pqb[base + (size_t)lane * NW + q]);
      Bs[o][lane] = b2f(pkb[base + (size_t)lane * NW + q]);
    } else {
      As[o][lane] = b2f(pqb[base + (size_t)q * NW + lane]);
      Bs[o][lane] = b2f(pkb[base + (size_t)q * NW + lane]);
    }
  }
  __syncthreads();
  int tc = (t & 15) * 4, tr = (t >> 4) * 4;
  float acc[4][4] = {};
  tile_mac(As, Bs, acc, tc, tr);
#pragma unroll
  for (int i = 0; i < 4; ++i)
#pragma unroll
    for (int j = 0; j < 4; ++j) {
      if (isH) {
        int h = tc + i, g = tr + j;
        float v = (h == g) ? -1e30f : acc[i][j];
        att[((size_t)(b * 64 + h) * 64 + q) * 128 + g] = v;
      } else {
        int w = tc + i, f = tr + j;
        att[((size_t)(b * 64 + q) * 64 + w) * 128 + 64 + f] = acc[i][j];
      }
    }
}

__global__ __launch_bounds__(256) void softmax_kernel(float* __restrict__ att) {
  int wave = threadIdx.x >> 6, lane = threadIdx.x & 63;
  int p = blockIdx.x * 4 + wave;
  float* row = att + (size_t)p * 128;
  float v0 = row[lane], v1 = row[lane + 64];
  float m = fmaxf(v0, v1);
#pragma unroll
  for (int off = 32; off; off >>= 1) m = fmaxf(m, __shfl_xor(m, off));
  float e0 = __expf(v0 - m), e1 = __expf(v1 - m);
  float s = e0 + e1;
#pragma unroll
  for (int off = 32; off; off >>= 1) s += __shfl_xor(s, off);
  float inv = 1.0f / s;
  row[lane] = e0 * inv;
  row[lane + 64] = e1 * inv;
}

__global__ __launch_bounds__(256) void transpose_kernel(const bf16* __restrict__ in,
                                                        bf16* __restrict__ out) {
  __shared__ float s[64][65];
  int lane = threadIdx.x & 63, row4 = threadIdx.x >> 6;
  const bf16* ip = in + (size_t)blockIdx.x * 4096;
  bf16* op = out + (size_t)blockIdx.x * 4096;
  for (int r = row4; r < 64; r += 4) s[r][lane] = b2f(ip[r * 64 + lane]);
  __syncthreads();
  for (int r = row4; r < 64; r += 4) op[r * 64 + lane] = f2b(s[lane][r]);
}

// ---- MFMA apply. mode 0: t1T[b,c,q,h] = sum_g pvT[b,c,q,g]*attH[b,h,q,g] (bf16 ws)
//      mode 1 (fused combine): out[b,c,q,w] = gamma*(sum_f pv[b,c,q*64+f]*attW
//              + t1T[b,c,w,q]) + value[b,c,q*64+w]   (f32 d_out)
__global__ __launch_bounds__(256) void apply_mfma(const bf16* __restrict__ pva,
                                                  const float* __restrict__ att,
                                                  const bf16* __restrict__ t1T,
                                                  const float* __restrict__ value,
                                                  const float* __restrict__ gamma,
                                                  void* outp, int mode, int strided) {
  __shared__ __align__(16) __bf16 As[64 * 72];
  __shared__ __align__(16) __bf16 Bs[64 * 72];
  int t = threadIdx.x;
  int b = blockIdx.x >> 6, q = blockIdx.x & 63;
  int c0 = blockIdx.y * 64;
  int wave = t >> 6, lane = t & 63;
  int row16 = lane & 15, quad = lane >> 4;
  // stage A (pv or pvT rows, bf16, k-contiguous)
#pragma unroll
  for (int ii = 0; ii < 2; ++ii) {
    int i = t + ii * 256;
    int m = i >> 3, ch = i & 7;
    if (!strided) {
      *(uint4*)&As[m * 72 + ch * 8] =
          *(const uint4*)&pva[((size_t)(b * NC + c0 + m) * 64 + q) * 64 + ch * 8];
    } else {  // compact mode0: pv[b,c,g,q] stride-64 scalar loads
      union { __bf16 h[8]; uint4 u; } pk;
#pragma unroll
      for (int j = 0; j < 8; ++j)
        pk.h[j] = (__bf16)b2f(pva[(size_t)(b * NC + c0 + m) * 4096 +
                                  (size_t)(ch * 8 + j) * 64 + q]);
      *(uint4*)&As[m * 72 + ch * 8] = pk.u;
    }
  }
  // stage B (att rows -> bf16)
#pragma unroll
  for (int ii = 0; ii < 4; ++ii) {
    int i = t + ii * 256;
    int n = i >> 4, ch4 = i & 15;
    const float* src = (mode == 0)
        ? &att[((size_t)(b * 64 + n) * 64 + q) * 128 + ch4 * 4]
        : &att[((size_t)(b * 64 + q) * 64 + n) * 128 + 64 + ch4 * 4];
    float4 v = *(const float4*)src;
    union { __bf16 h[4]; uint2 u; } pk;
    pk.h[0] = (__bf16)v.x; pk.h[1] = (__bf16)v.y;
    pk.h[2] = (__bf16)v.z; pk.h[3] = (__bf16)v.w;
    *(uint2*)&Bs[n * 72 + ch4 * 4] = pk.u;
  }
  __syncthreads();
  v4f acc[4] = {};
#pragma unroll
  for (int ks = 0; ks < 2; ++ks) {
    v8bf af = *(const v8bf*)&As[(wave * 16 + row16) * 72 + ks * 32 + quad * 8];
#pragma unroll
    for (int ni = 0; ni < 4; ++ni) {
      v8bf bfr = *(const v8bf*)&Bs[(ni * 16 + row16) * 72 + ks * 32 + quad * 8];
      acc[ni] = __builtin_amdgcn_mfma_f32_16x16x32_bf16(af, bfr, acc[ni], 0, 0, 0);
    }
  }
  if (mode == 0) {
    bf16* o = (bf16*)outp;
#pragma unroll
    for (int ni = 0; ni < 4; ++ni)
#pragma unroll
      for (int r = 0; r < 4; ++r) {
        int c = c0 + wave * 16 + quad * 4 + r;
        int h = row16 + ni * 16;
        o[((size_t)(b * NC + c) * 64 + q) * 64 + h] = f2b(acc[ni][r]);
      }
  } else {
    float* o = (float*)outp;
    float g = gamma[0];
#pragma unroll
    for (int ni = 0; ni < 4; ++ni)
#pragma unroll
      for (int r = 0; r < 4; ++r) {
        int c = c0 + wave * 16 + quad * 4 + r;
        int w = row16 + ni * 16;
        float t1v = b2f(t1T[((size_t)(b * NC + c) * 64 + w) * 64 + q]);
        float vv = value[(size_t)(b * NC + c) * 4096 + q * 64 + w];
        o[(size_t)(b * NC + c) * 4096 + q * 64 + w] = g * (acc[ni][r] + t1v) + vv;
      }
  }
}

extern "C" void kernel_launch(void* const* d_in, const int* in_sizes, int n_in,
                              void* d_out, int out_size, void* d_ws, size_t ws_size,
                              hipStream_t stream) {
  const float* query = (const float*)d_in[0];
  const float* key_t = (const float*)d_in[1];
  const float* value = (const float*)d_in[2];
  const float* Wq    = (const float*)d_in[3];
  const float* bq    = (const float*)d_in[4];
  const float* Wk    = (const float*)d_in[5];
  const float* bk    = (const float*)d_in[6];
  const float* Wv    = (const float*)d_in[7];
  const float* bv    = (const float*)d_in[8];
  const float* gamma = (const float*)d_in[9];
  float* out = (float*)d_out;

  // ws (MiB): pq@0(4) pk@4(4) att@8(16,f32) pv@24(32) [full: pvT@56(32) vSLOT@88(32)]
  //           [compact: vSLOT@56(32)]. vT lives in vSLOT until gemm_nt completes,
  //           then t1T reuses the same slot. Wb (0.5 MiB) borrows the pq slot
  //           (pq is written later, after gemm_nt). full=120 MiB, compact=88 MiB.
  char* ws = (char*)d_ws;
  bool full = ws_size >= (120ull << 20);
  bf16*  pq  = (bf16*)(ws);
  bf16*  Wb  = (bf16*)(ws);                      // dead before pq is written
  bf16*  pk  = (bf16*)(ws + (4ull << 20));
  float* att = (float*)(ws + (8ull << 20));
  bf16*  pv  = (bf16*)(ws + (24ull << 20));
  bf16*  pvT = (bf16*)(ws + (56ull << 20));
  bf16*  vT  = (bf16*)(ws + ((full ? 88ull : 56ull) << 20));
  bf16*  t1T = vT;                               // reuses slot after vT dies

  dim3 blk(256);
  prep_kernel<<<4096 + 256, blk, 0, stream>>>(value, Wv, vT, Wb);
  gemm_nt<<<dim3(NB * 32, 4), blk, 0, stream>>>(Wb, vT, bv, pv);
  if (full) transpose_kernel<<<NB * NC, blk, 0, stream>>>(pv, pvT);
  proj_mfma<64, 256><<<dim3(NB * 16, 1, 2), blk, 0, stream>>>(
      query, Wq, bq, pq, key_t, Wk, bk, pk, NI);
  score_kernel<<<dim3(NB * 64, 2), blk, 0, stream>>>(pq, pk, att);
  softmax_kernel<<<NB * NHW / 4, blk, 0, stream>>>(att);
  apply_mfma<<<dim3(NB * 64, 8), blk, 0, stream>>>(
      full ? pvT : pv, att, nullptr, value, gamma, t1T, 0, full ? 0 : 1);
  apply_mfma<<<dim3(NB * 64, 8), blk, 0, stream>>>(
      pv, att, t1T, value, gamma, out, 1, 0);
}